// Round 1
// baseline (4311.034 us; speedup 1.0000x reference)
//
#include <hip/hip_runtime.h>

#define U_NUM 359347
#define I_NUM 292589
#define DDIM  64
#define NNZ_N 4000000
#define BATCH 32768
#define LAM_F 0.001f

__device__ __forceinline__ float leaky(float x) { return x > 0.f ? x : 0.1f * x; }

// One wave (64 lanes) per edge: lane d handles dim d.
// out[rows[e]][d] += vals[e] * x[cols[e]][d]
__global__ __launch_bounds__(256) void spmm_atomic_k(
    const int* __restrict__ rows, const int* __restrict__ cols,
    const float* __restrict__ vals, const float* __restrict__ x,
    float* __restrict__ out, int nnz)
{
    int e = blockIdx.x * 4 + (threadIdx.x >> 6);
    if (e >= nnz) return;
    int lane = threadIdx.x & 63;
    int r = rows[e], c = cols[e];
    float v = vals[e];
    atomicAdd(&out[(size_t)r * DDIM + lane], v * x[(size_t)c * DDIM + lane]);
}

// acc = relu(acc + base * deg[row]), float4 over rows*64 elements (n4 = rows*16)
__global__ __launch_bounds__(256) void relu_resid_k(
    float* __restrict__ acc, const float* __restrict__ base,
    const float* __restrict__ deg, size_t n4)
{
    size_t i = (size_t)blockIdx.x * 256 + threadIdx.x;
    if (i >= n4) return;
    size_t row = i >> 4;
    float d = deg[row];
    float4 a = reinterpret_cast<float4*>(acc)[i];
    const float4 b = reinterpret_cast<const float4*>(base)[i];
    a.x = fmaxf(fmaf(b.x, d, a.x), 0.f);
    a.y = fmaxf(fmaf(b.y, d, a.y), 0.f);
    a.z = fmaxf(fmaf(b.z, d, a.z), 0.f);
    a.w = fmaxf(fmaf(b.w, d, a.w), 0.f);
    reinterpret_cast<float4*>(acc)[i] = a;
}

// sum over n elements of (w0*e + w1*g1 + w2*g2)^2 -> atomicAdd(acc)
__global__ __launch_bounds__(256) void l2_reduce_k(
    const float* __restrict__ e, const float* __restrict__ g1,
    const float* __restrict__ g2, const float* __restrict__ add_w,
    size_t n, float* __restrict__ acc)
{
    float w0 = add_w[0], w1 = add_w[1], w2 = add_w[2];
    float s = 0.f;
    size_t stride = (size_t)gridDim.x * 256;
    for (size_t i = (size_t)blockIdx.x * 256 + threadIdx.x; i < n; i += stride) {
        float g = fmaf(w0, e[i], fmaf(w1, g1[i], w2 * g2[i]));
        s = fmaf(g, g, s);
    }
    for (int off = 32; off; off >>= 1) s += __shfl_down(s, off);
    __shared__ float wsum[4];
    int lane = threadIdx.x & 63, wv = threadIdx.x >> 6;
    if (lane == 0) wsum[wv] = s;
    __syncthreads();
    if (threadIdx.x == 0)
        atomicAdd(acc, wsum[0] + wsum[1] + wsum[2] + wsum[3]);
}

// One wave per batch sample: recombine gcn row, 2-layer leaky MLP for both
// user and item sides, dot product, squared error -> atomicAdd(sse)
__global__ __launch_bounds__(256) void batch_mlp_k(
    const int* __restrict__ user0, const int* __restrict__ item0,
    const float* __restrict__ eu, const float* __restrict__ g1u, const float* __restrict__ g2u,
    const float* __restrict__ ei, const float* __restrict__ g1i, const float* __restrict__ g2i,
    const float* __restrict__ add_w,
    const float* __restrict__ fw1, const float* __restrict__ fb1,
    const float* __restrict__ fw2, const float* __restrict__ fb2,
    const float* __restrict__ ub, const float* __restrict__ ib,
    const float* __restrict__ avg, const float* __restrict__ ratings,
    float* __restrict__ sse_acc)
{
    __shared__ float s_x[4][64];
    __shared__ float s_h[4][128];
    int wv = threadIdx.x >> 6, lane = threadIdx.x & 63;
    int b = blockIdx.x * 4 + wv;
    float w0 = add_w[0], w1 = add_w[1], w2 = add_w[2];
    float sv0 = 0.f, sv1 = 0.f;
#pragma unroll
    for (int side = 0; side < 2; ++side) {
        int idx = side ? item0[b] : user0[b];
        const float* E  = side ? ei  : eu;
        const float* G1 = side ? g1i : g1u;
        const float* G2 = side ? g2i : g2u;
        size_t base = (size_t)idx * 64;
        s_x[wv][lane] = fmaf(w0, E[base + lane], fmaf(w1, G1[base + lane], w2 * G2[base + lane]));
        __syncthreads();
        float h0 = fb1[lane], h1 = fb1[lane + 64];
#pragma unroll 8
        for (int d = 0; d < 64; ++d) {
            float xv = s_x[wv][d];
            h0 = fmaf(fw1[lane * 64 + d], xv, h0);
            h1 = fmaf(fw1[(lane + 64) * 64 + d], xv, h1);
        }
        s_h[wv][lane]      = leaky(h0);
        s_h[wv][lane + 64] = leaky(h1);
        __syncthreads();
        float o = fb2[lane];
#pragma unroll 8
        for (int k = 0; k < 128; ++k)
            o = fmaf(fw2[lane * 128 + k], s_h[wv][k], o);
        o = leaky(o);
        if (side == 0) sv0 = o; else sv1 = o;
        __syncthreads();  // protect s_x/s_h before next side / reuse
    }
    float p = sv0 * sv1;
    for (int off = 32; off; off >>= 1) p += __shfl_down(p, off);
    __shared__ float s_p[4];
    if (lane == 0) {
        float pred = p + ub[user0[b]] + ib[item0[b]] + avg[0];
        float diff = pred - ratings[b];
        s_p[wv] = diff * diff;
    }
    __syncthreads();
    if (threadIdx.x == 0)
        atomicAdd(sse_acc, s_p[0] + s_p[1] + s_p[2] + s_p[3]);
}

__global__ void finalize_k(const float* __restrict__ acc, float* __restrict__ out)
{
    out[0] = acc[2] / (float)BATCH
           + LAM_F * (acc[0] / (float)((double)U_NUM * 64.0))
           + LAM_F * (acc[1] / (float)((double)I_NUM * 64.0));
}

extern "C" void kernel_launch(void* const* d_in, const int* in_sizes, int n_in,
                              void* d_out, int out_size, void* d_ws, size_t ws_size,
                              hipStream_t stream)
{
    const int*   ui_rows = (const int*)d_in[0];
    const int*   ui_cols = (const int*)d_in[1];
    const float* ui_vals = (const float*)d_in[2];
    const float* iu_vals = (const float*)d_in[3];
    const float* d_i     = (const float*)d_in[4];
    const float* d_j     = (const float*)d_in[5];
    const float* eu      = (const float*)d_in[6];
    const float* ei      = (const float*)d_in[7];
    const float* add_w   = (const float*)d_in[8];
    const float* fw1     = (const float*)d_in[9];
    const float* fb1     = (const float*)d_in[10];
    const float* fw2     = (const float*)d_in[11];
    const float* fb2     = (const float*)d_in[12];
    const float* ub      = (const float*)d_in[13];
    const float* ib      = (const float*)d_in[14];
    const float* avg     = (const float*)d_in[15];
    const int*   user0   = (const int*)d_in[16];
    const int*   item0   = (const int*)d_in[17];
    const float* ratings = (const float*)d_in[18];

    const size_t U64 = (size_t)U_NUM * 64;
    const size_t I64 = (size_t)I_NUM * 64;
    float* g1u = (float*)d_ws;
    float* g2u = g1u + U64;
    float* g1i = g2u + U64;
    float* g2i = g1i + I64;
    float* acc = g2i + I64;   // [0]=sum_u, [1]=sum_i, [2]=sse

    size_t total_bytes = (2 * U64 + 2 * I64 + 8) * sizeof(float);
    hipMemsetAsync(d_ws, 0, total_bytes, stream);

    dim3 blk(256);
    int spmm_grid = (NNZ_N + 3) / 4;

    // layer 1
    spmm_atomic_k<<<spmm_grid, blk, 0, stream>>>(ui_rows, ui_cols, ui_vals, ei, g1u, NNZ_N);
    spmm_atomic_k<<<spmm_grid, blk, 0, stream>>>(ui_cols, ui_rows, iu_vals, eu, g1i, NNZ_N);
    relu_resid_k<<<(U_NUM * 16 + 255) / 256, blk, 0, stream>>>(g1u, eu, d_i, (size_t)U_NUM * 16);
    relu_resid_k<<<(I_NUM * 16 + 255) / 256, blk, 0, stream>>>(g1i, ei, d_j, (size_t)I_NUM * 16);

    // layer 2
    spmm_atomic_k<<<spmm_grid, blk, 0, stream>>>(ui_rows, ui_cols, ui_vals, g1i, g2u, NNZ_N);
    spmm_atomic_k<<<spmm_grid, blk, 0, stream>>>(ui_cols, ui_rows, iu_vals, g1u, g2i, NNZ_N);
    relu_resid_k<<<(U_NUM * 16 + 255) / 256, blk, 0, stream>>>(g2u, g1u, d_i, (size_t)U_NUM * 16);
    relu_resid_k<<<(I_NUM * 16 + 255) / 256, blk, 0, stream>>>(g2i, g1i, d_j, (size_t)I_NUM * 16);

    // reductions
    l2_reduce_k<<<2048, blk, 0, stream>>>(eu, g1u, g2u, add_w, U64, acc + 0);
    l2_reduce_k<<<2048, blk, 0, stream>>>(ei, g1i, g2i, add_w, I64, acc + 1);
    batch_mlp_k<<<BATCH / 4, blk, 0, stream>>>(user0, item0, eu, g1u, g2u, ei, g1i, g2i,
                                               add_w, fw1, fb1, fw2, fb2, ub, ib, avg,
                                               ratings, acc + 2);
    finalize_k<<<1, 1, 0, stream>>>(acc, (float*)d_out);
}